// Round 1
// baseline (481.315 us; speedup 1.0000x reference)
//
#include <hip/hip_runtime.h>
#include <hip/hip_bf16.h>

typedef short s16x8 __attribute__((ext_vector_type(8)));
typedef float f32x4 __attribute__((ext_vector_type(4)));
typedef unsigned short u16;

#define B_ 4
#define S_ 2048
#define E_ 1024
#define H_ 16
#define DH_ 64

__device__ __forceinline__ u16 f2b(float f) {
  union { float f; unsigned u; } x; x.f = f;
  unsigned r = (x.u + 0x7fffu + ((x.u >> 16) & 1u)) >> 16;
  return (u16)r;
}

__device__ __forceinline__ void async16(const void* g, void* l) {
  __builtin_amdgcn_global_load_lds((const __attribute__((address_space(1))) void*)g,
                                   (__attribute__((address_space(3))) void*)l,
                                   16, 0, 0);
}

// ---------------- cast f32 -> bf16 (vectorized) ----------------
__global__ __launch_bounds__(256) void k_cast(const float* __restrict__ in,
                                              u16* __restrict__ out, int n4) {
  int i = blockIdx.x * 256 + threadIdx.x;
  if (i >= n4) return;
  float4 v = ((const float4*)in)[i];
  ushort4 o;
  o.x = f2b(v.x); o.y = f2b(v.y); o.z = f2b(v.z); o.w = f2b(v.w);
  ((ushort4*)out)[i] = o;
}

// ---------------- cast + transpose weight: W[K][N] f32 -> Wt[N][K] bf16 ----------------
__global__ __launch_bounds__(256) void k_castT(const float* __restrict__ in,
                                               u16* __restrict__ out, int K, int N) {
  __shared__ float tile[32][33];
  int k0 = blockIdx.x * 32, n0 = blockIdx.y * 32;
  int tx = threadIdx.x, ty = threadIdx.y;
#pragma unroll
  for (int i = 0; i < 32; i += 8)
    tile[ty + i][tx] = in[(long)(k0 + ty + i) * N + n0 + tx];
  __syncthreads();
#pragma unroll
  for (int i = 0; i < 32; i += 8)
    out[(long)(n0 + ty + i) * K + k0 + tx] = f2b(tile[tx][ty + i]);
}

// ---------------- GEMM: C[M,N] = A[M,K](bf16) * Bt[N,K]^T(bf16)  (+bias)(+relu) ----------------
// 128x128 tile, BK=32, 4 waves (each 64x64 = 4x4 frags of 16x16x32 MFMA), m97 structure.
__global__ __launch_bounds__(256, 2) void k_gemm(
    const u16* __restrict__ A, const u16* __restrict__ Bt,
    int N, int K,
    const float* __restrict__ bias, int relu,
    float* __restrict__ outF, u16* __restrict__ outB) {
  __shared__ __align__(16) u16 Al[128 * 32];
  __shared__ __align__(16) u16 Bl[128 * 32];
  const int t = threadIdx.x;
  const int lane = t & 63, w = t >> 6;
  const int g = lane >> 4, li = lane & 15;
  const int wr = w >> 1, wc = w & 1;
  const int bm = blockIdx.x * 128, bn = blockIdx.y * 128;

  f32x4 acc[4][4] = {};

  // staging: idx = p*256 + t ; row = idx/4 ; col8 = (idx%4)*8 ; lds dest = wave base + lane*16
  const long ar0 = bm + (t >> 2), ar1 = bm + ((256 + t) >> 2);
  const long br0 = bn + (t >> 2), br1 = bn + ((256 + t) >> 2);
  const int c0 = (t & 3) * 8, c1 = ((256 + t) & 3) * 8;
  u16* aD0 = &Al[(w * 64) * 8];
  u16* aD1 = &Al[(256 + w * 64) * 8];
  u16* bD0 = &Bl[(w * 64) * 8];
  u16* bD1 = &Bl[(256 + w * 64) * 8];

  for (int kt = 0; kt < K; kt += 32) {
    async16(&A[ar0 * K + kt + c0], aD0);
    async16(&A[ar1 * K + kt + c1], aD1);
    async16(&Bt[br0 * K + kt + c0], bD0);
    async16(&Bt[br1 * K + kt + c1], bD1);
    __syncthreads();
    s16x8 af[4], bf[4];
#pragma unroll
    for (int mi = 0; mi < 4; ++mi)
      af[mi] = *(const s16x8*)&Al[(wr * 64 + mi * 16 + li) * 32 + g * 8];
#pragma unroll
    for (int nf = 0; nf < 4; ++nf)
      bf[nf] = *(const s16x8*)&Bl[(wc * 64 + nf * 16 + li) * 32 + g * 8];
#pragma unroll
    for (int mi = 0; mi < 4; ++mi)
#pragma unroll
      for (int nf = 0; nf < 4; ++nf)
        acc[mi][nf] = __builtin_amdgcn_mfma_f32_16x16x32_bf16(af[mi], bf[nf], acc[mi][nf], 0, 0, 0);
    __syncthreads();
  }

#pragma unroll
  for (int mi = 0; mi < 4; ++mi)
#pragma unroll
    for (int nf = 0; nf < 4; ++nf) {
      int col = bn + wc * 64 + nf * 16 + li;
      float bv = bias ? bias[col] : 0.f;
#pragma unroll
      for (int r = 0; r < 4; ++r) {
        long row = bm + wr * 64 + mi * 16 + g * 4 + r;
        float v = acc[mi][nf][r] + bv;
        if (relu) v = fmaxf(v, 0.f);
        if (outF) outF[row * N + col] = v;
        if (outB) outB[row * N + col] = f2b(v);
      }
    }
}

// ---------------- flash attention ----------------
// grid (S/128, B*H); 4 waves, each owns 32 q-rows; key tiles of 64.
__global__ __launch_bounds__(256, 2) void k_attn(
    const u16* __restrict__ Q, const u16* __restrict__ Kg, const u16* __restrict__ Vg,
    const int* __restrict__ mask, u16* __restrict__ ctx) {
  __shared__ __align__(16) u16 Kl[64 * 72];   // [key][dh], pad 72
  __shared__ __align__(16) u16 Vl[64 * 72];   // [dh][key], pad 72 (transposed)
  __shared__ __align__(16) u16 Pl[4 * 32 * 72];
  const int t = threadIdx.x;
  const int lane = t & 63, w = t >> 6;
  const int g = lane >> 4, li = lane & 15;
  const int bh = blockIdx.y;
  const int b = bh >> 4, h = bh & 15;
  const int q0 = blockIdx.x * 128 + w * 32;

  // Q fragments live in registers for the whole kernel
  s16x8 qf[2][2];
#pragma unroll
  for (int mi = 0; mi < 2; ++mi)
#pragma unroll
    for (int kk = 0; kk < 2; ++kk)
      qf[mi][kk] = *(const s16x8*)&Q[((long)(b * S_ + q0 + mi * 16 + li) * H_ + h) * DH_ + kk * 32 + g * 8];

  float m_s[2][4], l_s[2][4];
  f32x4 o_acc[2][4] = {};
#pragma unroll
  for (int mi = 0; mi < 2; ++mi)
#pragma unroll
    for (int r = 0; r < 4; ++r) { m_s[mi][r] = -1e30f; l_s[mi][r] = 0.f; }

  const float scale = 0.125f;  // 1/sqrt(64)
  u16* Pw = &Pl[w * 32 * 72];

  for (int kt = 0; kt < S_; kt += 64) {
    {  // stage K [key][dh] (coalesced 32B per thread)
      int key = t >> 2, cc = (t & 3) * 16;
      const u16* src = &Kg[((long)(b * S_ + kt + key) * H_ + h) * DH_ + cc];
      *(s16x8*)&Kl[key * 72 + cc] = *(const s16x8*)src;
      *(s16x8*)&Kl[key * 72 + cc + 8] = *(const s16x8*)(src + 8);
      // stage V transposed [dh][key]
      int key2 = t & 63, dhg = t >> 6;
      const u16* vs = &Vg[((long)(b * S_ + kt + key2) * H_ + h) * DH_ + dhg * 16];
      s16x8 v0 = *(const s16x8*)vs, v1 = *(const s16x8*)(vs + 8);
#pragma unroll
      for (int j = 0; j < 8; ++j) {
        Vl[(dhg * 16 + j) * 72 + key2] = (u16)v0[j];
        Vl[(dhg * 16 + 8 + j) * 72 + key2] = (u16)v1[j];
      }
    }
    __syncthreads();

    // S = Q K^T
    f32x4 sc[2][4] = {};
#pragma unroll
    for (int kk = 0; kk < 2; ++kk) {
      s16x8 kf[4];
#pragma unroll
      for (int nf = 0; nf < 4; ++nf)
        kf[nf] = *(const s16x8*)&Kl[(nf * 16 + li) * 72 + kk * 32 + g * 8];
#pragma unroll
      for (int mi = 0; mi < 2; ++mi)
#pragma unroll
        for (int nf = 0; nf < 4; ++nf)
          sc[mi][nf] = __builtin_amdgcn_mfma_f32_16x16x32_bf16(qf[mi][kk], kf[nf], sc[mi][nf], 0, 0, 0);
    }

    int mk[4];
#pragma unroll
    for (int nf = 0; nf < 4; ++nf) mk[nf] = mask[b * S_ + kt + nf * 16 + li];

    // online softmax: each 16-lane group owns rows g*4+r (+ mi*16)
#pragma unroll
    for (int mi = 0; mi < 2; ++mi) {
#pragma unroll
      for (int r = 0; r < 4; ++r) {
        float sv[4];
#pragma unroll
        for (int nf = 0; nf < 4; ++nf)
          sv[nf] = mk[nf] ? sc[mi][nf][r] * scale : -1e10f;
        float tmax = fmaxf(fmaxf(sv[0], sv[1]), fmaxf(sv[2], sv[3]));
#pragma unroll
        for (int xm = 8; xm >= 1; xm >>= 1) tmax = fmaxf(tmax, __shfl_xor(tmax, xm));
        float mnew = fmaxf(m_s[mi][r], tmax);
        float corr = __expf(m_s[mi][r] - mnew);
        float p[4], psum = 0.f;
#pragma unroll
        for (int nf = 0; nf < 4; ++nf) { p[nf] = __expf(sv[nf] - mnew); psum += p[nf]; }
#pragma unroll
        for (int xm = 8; xm >= 1; xm >>= 1) psum += __shfl_xor(psum, xm);
        l_s[mi][r] = l_s[mi][r] * corr + psum;
        m_s[mi][r] = mnew;
#pragma unroll
        for (int nf = 0; nf < 4; ++nf) o_acc[mi][nf][r] *= corr;
        int prow = mi * 16 + g * 4 + r;
#pragma unroll
        for (int nf = 0; nf < 4; ++nf) Pw[prow * 72 + nf * 16 + li] = f2b(p[nf]);
      }
    }

    // O += P V
#pragma unroll
    for (int kk = 0; kk < 2; ++kk) {
      s16x8 pa[2], vb[4];
#pragma unroll
      for (int mi = 0; mi < 2; ++mi)
        pa[mi] = *(const s16x8*)&Pw[(mi * 16 + li) * 72 + kk * 32 + g * 8];
#pragma unroll
      for (int nf = 0; nf < 4; ++nf)
        vb[nf] = *(const s16x8*)&Vl[(nf * 16 + li) * 72 + kk * 32 + g * 8];
#pragma unroll
      for (int mi = 0; mi < 2; ++mi)
#pragma unroll
        for (int nf = 0; nf < 4; ++nf)
          o_acc[mi][nf] = __builtin_amdgcn_mfma_f32_16x16x32_bf16(pa[mi], vb[nf], o_acc[mi][nf], 0, 0, 0);
    }
    __syncthreads();
  }

#pragma unroll
  for (int mi = 0; mi < 2; ++mi)
#pragma unroll
    for (int r = 0; r < 4; ++r) {
      float inv = 1.f / fmaxf(l_s[mi][r], 1e-30f);
      long qrow = (long)b * S_ + q0 + mi * 16 + g * 4 + r;
#pragma unroll
      for (int nf = 0; nf < 4; ++nf)
        ctx[(qrow * H_ + h) * DH_ + nf * 16 + li] = f2b(o_acc[mi][nf][r] * inv);
    }
}

// ---------------- fused residual + LayerNorm ----------------
__global__ __launch_bounds__(256) void k_ln(const float* __restrict__ a, const float* __restrict__ res,
                                            const float* __restrict__ gamma, const float* __restrict__ beta,
                                            float* __restrict__ outF, u16* __restrict__ outB) {
  const int row = blockIdx.x, t = threadIdx.x;
  const long base = (long)row * E_;
  float4 av = ((const float4*)(a + base))[t];
  float4 bv = ((const float4*)(res + base))[t];
  float4 s = make_float4(av.x + bv.x, av.y + bv.y, av.z + bv.z, av.w + bv.w);
  float ps = s.x + s.y + s.z + s.w;
  float pq = s.x * s.x + s.y * s.y + s.z * s.z + s.w * s.w;
#pragma unroll
  for (int xm = 32; xm >= 1; xm >>= 1) { ps += __shfl_xor(ps, xm); pq += __shfl_xor(pq, xm); }
  __shared__ float red[8];
  int w = t >> 6, lane = t & 63;
  if (lane == 0) { red[w] = ps; red[4 + w] = pq; }
  __syncthreads();
  ps = red[0] + red[1] + red[2] + red[3];
  pq = red[4] + red[5] + red[6] + red[7];
  float mu = ps * (1.f / E_);
  float rs = rsqrtf(pq * (1.f / E_) - mu * mu + 1e-5f);
  float4 gv = ((const float4*)gamma)[t];
  float4 be = ((const float4*)beta)[t];
  float4 o = make_float4((s.x - mu) * rs * gv.x + be.x, (s.y - mu) * rs * gv.y + be.y,
                         (s.z - mu) * rs * gv.z + be.z, (s.w - mu) * rs * gv.w + be.w);
  ((float4*)(outF + base))[t] = o;
  if (outB) {
    ushort4 ob; ob.x = f2b(o.x); ob.y = f2b(o.y); ob.z = f2b(o.z); ob.w = f2b(o.w);
    ((ushort4*)(outB + base))[t] = ob;
  }
}

extern "C" void kernel_launch(void* const* d_in, const int* in_sizes, int n_in,
                              void* d_out, int out_size, void* d_ws, size_t ws_size,
                              hipStream_t stream) {
  const float* x  = (const float*)d_in[0];
  const int* mask = (const int*)d_in[1];
  const float* wq = (const float*)d_in[2];
  const float* wk = (const float*)d_in[3];
  const float* wv = (const float*)d_in[4];
  const float* wo = (const float*)d_in[5];
  const float* bo = (const float*)d_in[6];
  const float* w1 = (const float*)d_in[7];
  const float* b1 = (const float*)d_in[8];
  const float* w2 = (const float*)d_in[9];
  const float* b2 = (const float*)d_in[10];
  const float* gamma = (const float*)d_in[11];
  const float* beta  = (const float*)d_in[12];
  float* out = (float*)d_out;

  char* ws = (char*)d_ws;
  const size_t MB = 1024ull * 1024ull;
  u16* xb  = (u16*)(ws + 0);         // 16MB, reused as ctx after QKV
  u16* wqt = (u16*)(ws + 16 * MB);
  u16* wkt = (u16*)(ws + 18 * MB);
  u16* wvt = (u16*)(ws + 20 * MB);
  u16* wot = (u16*)(ws + 22 * MB);
  u16* w1t = (u16*)(ws + 24 * MB);
  u16* w2t = (u16*)(ws + 26 * MB);
  u16* qb  = (u16*)(ws + 28 * MB);   // 16MB, reused as ff1 after attention
  u16* kb  = (u16*)(ws + 44 * MB);
  u16* vb  = (u16*)(ws + 60 * MB);
  float* ao = (float*)(ws + 76 * MB);  // 32MB, reused as ff2 after LN1
  float* hf = (float*)(ws + 108 * MB); // 32MB
  u16* hb  = (u16*)(ws + 140 * MB);    // 16MB   (peak 156MB)
  u16* ctx = xb;
  u16* ff1 = qb;
  float* ff2 = ao;

  const int n4 = B_ * S_ * E_ / 4;
  k_cast<<<n4 / 256, 256, 0, stream>>>(x, xb, n4);
  dim3 tg(E_ / 32, E_ / 32), tb(32, 8);
  k_castT<<<tg, tb, 0, stream>>>(wq, wqt, E_, E_);
  k_castT<<<tg, tb, 0, stream>>>(wk, wkt, E_, E_);
  k_castT<<<tg, tb, 0, stream>>>(wv, wvt, E_, E_);
  k_castT<<<tg, tb, 0, stream>>>(wo, wot, E_, E_);
  k_castT<<<tg, tb, 0, stream>>>(w1, w1t, E_, E_);
  k_castT<<<tg, tb, 0, stream>>>(w2, w2t, E_, E_);

  dim3 gg(64, 8);  // M=8192/128, N=1024/128
  k_gemm<<<gg, 256, 0, stream>>>(xb, wqt, 1024, 1024, nullptr, 0, nullptr, qb);
  k_gemm<<<gg, 256, 0, stream>>>(xb, wkt, 1024, 1024, nullptr, 0, nullptr, kb);
  k_gemm<<<gg, 256, 0, stream>>>(xb, wvt, 1024, 1024, nullptr, 0, nullptr, vb);

  k_attn<<<dim3(S_ / 128, B_ * H_), 256, 0, stream>>>(qb, kb, vb, mask, ctx);

  k_gemm<<<gg, 256, 0, stream>>>(ctx, wot, 1024, 1024, bo, 0, ao, nullptr);
  k_ln<<<B_ * S_, 256, 0, stream>>>(ao, x, gamma, beta, hf, hb);
  k_gemm<<<gg, 256, 0, stream>>>(hb, w1t, 1024, 1024, b1, 1, nullptr, ff1);
  k_gemm<<<gg, 256, 0, stream>>>(ff1, w2t, 1024, 1024, b2, 0, ff2, nullptr);
  k_ln<<<B_ * S_, 256, 0, stream>>>(ff2, hf, gamma, beta, out, nullptr);
}

// Round 2
// 353.733 us; speedup vs baseline: 1.3607x; 1.3607x over previous
//
#include <hip/hip_runtime.h>
#include <hip/hip_bf16.h>

typedef short s16x8 __attribute__((ext_vector_type(8)));
typedef float f32x4 __attribute__((ext_vector_type(4)));
typedef float f32x16 __attribute__((ext_vector_type(16)));
typedef unsigned short u16;

#define B_ 4
#define S_ 2048
#define E_ 1024
#define H_ 16
#define DH_ 64

__device__ __forceinline__ u16 f2b(float f) {
  union { float f; unsigned u; } x; x.f = f;
  unsigned r = (x.u + 0x7fffu + ((x.u >> 16) & 1u)) >> 16;
  return (u16)r;
}

__device__ __forceinline__ unsigned pk2(float lo, float hi) {
  __hip_bfloat162 h = __float22bfloat162_rn(float2{lo, hi});
  union { __hip_bfloat162 h; unsigned u; } c; c.h = h; return c.u;
}

// exchange: x' = lanes<32: x, lanes>=32: y from lane-32 ; y' = lanes<32: x from lane+32, lanes>=32: y
__device__ __forceinline__ void xswap(unsigned& x, unsigned& y, int hi) {
  unsigned xs = (unsigned)__shfl_xor((int)x, 32);
  unsigned ys = (unsigned)__shfl_xor((int)y, 32);
  unsigned nx = hi ? ys : x;
  unsigned ny = hi ? y : xs;
  x = nx; y = ny;
}

__device__ __forceinline__ void async16(const void* g, void* l) {
  __builtin_amdgcn_global_load_lds((const __attribute__((address_space(1))) void*)g,
                                   (__attribute__((address_space(3))) void*)l,
                                   16, 0, 0);
}

// ---------------- cast f32 -> bf16 ----------------
__global__ __launch_bounds__(256) void k_cast(const float* __restrict__ in,
                                              u16* __restrict__ out, int n4) {
  int i = blockIdx.x * 256 + threadIdx.x;
  if (i >= n4) return;
  float4 v = ((const float4*)in)[i];
  ushort4 o;
  o.x = f2b(v.x); o.y = f2b(v.y); o.z = f2b(v.z); o.w = f2b(v.w);
  ((ushort4*)out)[i] = o;
}

// ---------------- cast + transpose weight: W[K][N] f32 -> Wt[N][K] bf16 ----------------
__global__ __launch_bounds__(256) void k_castT(const float* __restrict__ in,
                                               u16* __restrict__ out, int K, int N) {
  __shared__ float tile[32][33];
  int k0 = blockIdx.x * 32, n0 = blockIdx.y * 32;
  int tx = threadIdx.x, ty = threadIdx.y;
#pragma unroll
  for (int i = 0; i < 32; i += 8)
    tile[ty + i][tx] = in[(long)(k0 + ty + i) * N + n0 + tx];
  __syncthreads();
#pragma unroll
  for (int i = 0; i < 32; i += 8)
    out[(long)(n0 + ty + i) * K + k0 + tx] = f2b(tile[tx][ty + i]);
}

// ---------------- GEMM: C[M,N] = A[M,K](bf16) * Bt[N,K]^T(bf16) ----------------
// mode 0: normal (bias/relu, outF/outB).  mode 1: fused-QKV permuted write to oq/ok/ov
// (bh-major [B,H,S,DH]), Q scaled by 0.125.
__global__ __launch_bounds__(256, 2) void k_gemm(
    const u16* __restrict__ A, const u16* __restrict__ Bt,
    int N, int K,
    const float* __restrict__ bias, int relu, int mode,
    float* __restrict__ outF, u16* __restrict__ outB,
    u16* __restrict__ oq, u16* __restrict__ ok, u16* __restrict__ ov) {
  __shared__ __align__(16) u16 Al[128 * 32];
  __shared__ __align__(16) u16 Bl[128 * 32];
  const int t = threadIdx.x;
  const int lane = t & 63, w = t >> 6;
  const int g = lane >> 4, li = lane & 15;
  const int wr = w >> 1, wc = w & 1;
  const int bm = blockIdx.x * 128, bn = blockIdx.y * 128;

  f32x4 acc[4][4] = {};

  const long ar0 = bm + (t >> 2), ar1 = bm + ((256 + t) >> 2);
  const long br0 = bn + (t >> 2), br1 = bn + ((256 + t) >> 2);
  const int c0 = (t & 3) * 8, c1 = ((256 + t) & 3) * 8;
  u16* aD0 = &Al[(w * 64) * 8];
  u16* aD1 = &Al[(256 + w * 64) * 8];
  u16* bD0 = &Bl[(w * 64) * 8];
  u16* bD1 = &Bl[(256 + w * 64) * 8];

  for (int kt = 0; kt < K; kt += 32) {
    async16(&A[ar0 * K + kt + c0], aD0);
    async16(&A[ar1 * K + kt + c1], aD1);
    async16(&Bt[br0 * K + kt + c0], bD0);
    async16(&Bt[br1 * K + kt + c1], bD1);
    __syncthreads();
    s16x8 af[4], bf[4];
#pragma unroll
    for (int mi = 0; mi < 4; ++mi)
      af[mi] = *(const s16x8*)&Al[(wr * 64 + mi * 16 + li) * 32 + g * 8];
#pragma unroll
    for (int nf = 0; nf < 4; ++nf)
      bf[nf] = *(const s16x8*)&Bl[(wc * 64 + nf * 16 + li) * 32 + g * 8];
#pragma unroll
    for (int mi = 0; mi < 4; ++mi)
#pragma unroll
      for (int nf = 0; nf < 4; ++nf)
        acc[mi][nf] = __builtin_amdgcn_mfma_f32_16x16x32_bf16(af[mi], bf[nf], acc[mi][nf], 0, 0, 0);
    __syncthreads();
  }

#pragma unroll
  for (int mi = 0; mi < 4; ++mi)
#pragma unroll
    for (int nf = 0; nf < 4; ++nf) {
      int col = bn + wc * 64 + nf * 16 + li;
      if (mode == 1) {
        int which = col >> 10, cc = col & 1023;
        int hh = cc >> 6, dd = cc & 63;
        u16* dst = which == 0 ? oq : (which == 1 ? ok : ov);
        float scl = which == 0 ? 0.125f : 1.f;
#pragma unroll
        for (int r = 0; r < 4; ++r) {
          long row = bm + wr * 64 + mi * 16 + g * 4 + r;
          int b2 = (int)(row >> 11), ss = (int)(row & 2047);
          dst[(((long)b2 * H_ + hh) * S_ + ss) * DH_ + dd] = f2b(acc[mi][nf][r] * scl);
        }
      } else {
        float bv = bias ? bias[col] : 0.f;
#pragma unroll
        for (int r = 0; r < 4; ++r) {
          long row = bm + wr * 64 + mi * 16 + g * 4 + r;
          float v = acc[mi][nf][r] + bv;
          if (relu) v = fmaxf(v, 0.f);
          if (outF) outF[row * N + col] = v;
          if (outB) outB[row * N + col] = f2b(v);
        }
      }
    }
}

// ---------------- flash attention, swapped-QK^T 32x32 structure ----------------
// grid (B*H, S/256); 8 waves x 32 q-rows. Q/K/V in [B,H,S,DH] bf16, Q pre-scaled by 1/8.
// Per tile (64 keys):
//   S^T[key][q] = sum_dh K[key][dh] * Q^T[dh][q]   (A=K from swizzled LDS, B=Q regs)
//   lane(q=lane&31, hi=lane>>5) holds S for keys st*32 + (r&3)+8*(r>>2)+4*hi, r=0..15, st=0..1
//   softmax in-register (partner exchange via shfl_xor 32); defer-max THR=8
//   P repacked to PV A-operand via cvt_pk + half-exchange; V^T from padded LDS.
__global__ __launch_bounds__(512, 1) void k_attn(
    const u16* __restrict__ Q, const u16* __restrict__ Kg, const u16* __restrict__ Vg,
    const int* __restrict__ mask, u16* __restrict__ ctx) {
  __shared__ __align__(16) u16 Kl[2][64 * 64];   // [key][dh], XOR-swizzled rows
  __shared__ __align__(16) u16 Vt[2][64 * 72];   // [dh][key+pad8]
  __shared__ __align__(16) float MBs[S_];        // additive mask bias, whole sequence
  __shared__ __align__(16) float BC[8 * 32];     // per-wave broadcast (corr / 1/l)
  const int t = threadIdx.x;
  const int lane = t & 63, wid = t >> 6;
  const int q = lane & 31, hi = lane >> 5;
  const int bh = blockIdx.x;
  const int b = bh >> 4, h = bh & 15;
  const long bhoff = (long)bh * S_ * DH_;
  const int q0 = blockIdx.y * 256 + wid * 32;
  const int skey = t >> 3, sdj = t & 7;

  {  // stage mask bias once: 512 threads x int4
    int4 m4 = ((const int4*)(mask + (long)b * S_))[t];
    float4 f;
    f.x = m4.x ? 0.f : -1e10f; f.y = m4.y ? 0.f : -1e10f;
    f.z = m4.z ? 0.f : -1e10f; f.w = m4.w ? 0.f : -1e10f;
    ((float4*)MBs)[t] = f;
  }

  // Q fragments (B-operand): lane holds Q[q][c*16 + hi*8 .. +7]
  s16x8 qf[4];
  {
    const u16* Qp = Q + bhoff + (long)(q0 + q) * DH_;
#pragma unroll
    for (int c = 0; c < 4; ++c) qf[c] = *(const s16x8*)(Qp + c * 16 + hi * 8);
  }

  s16x8 kreg, vreg;
  // K: coalesced (8 lanes cover one key row); V: per-wave d-group, lane=key (scattered 16B)
#define LOADKV(KT) { \
    kreg = *(const s16x8*)(Kg + bhoff + (long)((KT) + skey) * DH_ + sdj * 8); \
    vreg = *(const s16x8*)(Vg + bhoff + (long)((KT) + lane) * DH_ + wid * 8); }
#define WRITEKV(BUF) { \
    *(s16x8*)((char*)&Kl[BUF][0] + skey * 128 + ((sdj * 16) ^ ((skey & 7) << 4))) = kreg; \
    _Pragma("unroll") \
    for (int j = 0; j < 8; ++j) Vt[BUF][(wid * 8 + j) * 72 + lane] = (u16)vreg[j]; }

  LOADKV(0);
  WRITEKV(0);
  __syncthreads();

  f32x16 o0 = {}, o1 = {};
  float m_run = -1e30f, l_run = 0.f;
  int cur = 0;
  const int swz = (q & 7) << 4;

  for (int kt = 0; kt < S_; kt += 64) {
    if (kt + 64 < S_) LOADKV(kt + 64);

    // ---- S^T = K * Q^T ----
    f32x16 s0 = {}, s1 = {};
#pragma unroll
    for (int c = 0; c < 4; ++c) {
      s16x8 kf0 = *(const s16x8*)((char*)&Kl[cur][0] + q * 128 + ((c * 32 + hi * 16) ^ swz));
      s16x8 kf1 = *(const s16x8*)((char*)&Kl[cur][0] + (32 + q) * 128 + ((c * 32 + hi * 16) ^ swz));
      s0 = __builtin_amdgcn_mfma_f32_32x32x16_bf16(kf0, qf[c], s0, 0, 0, 0);
      s1 = __builtin_amdgcn_mfma_f32_32x32x16_bf16(kf1, qf[c], s1, 0, 0, 0);
    }

    // ---- mask bias + row max (in-lane + partner) ----
    float p[32];
    float tmax = -1e30f;
#pragma unroll
    for (int g = 0; g < 4; ++g) {
      f32x4 mb0 = *(const f32x4*)&MBs[kt + g * 8 + hi * 4];
      f32x4 mb1 = *(const f32x4*)&MBs[kt + 32 + g * 8 + hi * 4];
#pragma unroll
      for (int e = 0; e < 4; ++e) {
        float v0 = s0[g * 4 + e] + mb0[e];
        float v1 = s1[g * 4 + e] + mb1[e];
        p[g * 4 + e] = v0; p[16 + g * 4 + e] = v1;
        tmax = fmaxf(tmax, fmaxf(v0, v1));
      }
    }
    tmax = fmaxf(tmax, __shfl_xor(tmax, 32));

    if (!__all(tmax <= m_run + 8.f)) {  // defer-max: rescale only when max grew
      float mnew = fmaxf(m_run, tmax);
      float corr = __expf(m_run - mnew);
      m_run = mnew; l_run *= corr;
      if (lane < 32) BC[wid * 32 + q] = corr;
      asm volatile("s_waitcnt lgkmcnt(0)" ::: "memory");
#pragma unroll
      for (int g = 0; g < 4; ++g) {
        f32x4 cv = *(const f32x4*)&BC[wid * 32 + g * 8 + hi * 4];
#pragma unroll
        for (int e = 0; e < 4; ++e) { o0[g * 4 + e] *= cv[e]; o1[g * 4 + e] *= cv[e]; }
      }
    }

    // ---- exp + partial row-sum (partner-combined at the end) ----
    float ps = 0.f;
#pragma unroll
    for (int j = 0; j < 32; ++j) {
      float pv = __expf(p[j] - m_run);
      p[j] = pv; ps += pv;
    }
    l_run += ps;

    // ---- O += P V : repack P into A-operand, V^T from LDS as B ----
#pragma unroll
    for (int c = 0; c < 4; ++c) {
      unsigned X1 = pk2(p[c * 8 + 0], p[c * 8 + 1]);
      unsigned X2 = pk2(p[c * 8 + 2], p[c * 8 + 3]);
      unsigned Y1 = pk2(p[c * 8 + 4], p[c * 8 + 5]);
      unsigned Y2 = pk2(p[c * 8 + 6], p[c * 8 + 7]);
      xswap(X1, Y1, hi); xswap(X2, Y2, hi);
      union { unsigned u[4]; s16x8 v; } pu;
      pu.u[0] = X1; pu.u[1] = X2; pu.u[2] = Y1; pu.u[3] = Y2;
      s16x8 vb0 = *(const s16x8*)&Vt[cur][(long)q * 72 + c * 16 + hi * 8];
      s16x8 vb1 = *(const s16x8*)&Vt[cur][(long)(32 + q) * 72 + c * 16 + hi * 8];
      o0 = __builtin_amdgcn_mfma_f32_32x32x16_bf16(pu.v, vb0, o0, 0, 0, 0);
      o1 = __builtin_amdgcn_mfma_f32_32x32x16_bf16(pu.v, vb1, o1, 0, 0, 0);
    }

    if (kt + 64 < S_) WRITEKV(cur ^ 1);
    __syncthreads();
    cur ^= 1;
  }

  // ---- epilogue: combine l with partner, broadcast 1/l per q-row, store ----
  l_run += __shfl_xor(l_run, 32);
  float inv = 1.f / fmaxf(l_run, 1e-30f);
  if (lane < 32) BC[wid * 32 + q] = inv;
  asm volatile("s_waitcnt lgkmcnt(0)" ::: "memory");
#pragma unroll
  for (int g = 0; g < 4; ++g) {
    f32x4 iv = *(const f32x4*)&BC[wid * 32 + g * 8 + hi * 4];
#pragma unroll
    for (int e = 0; e < 4; ++e) {
      int qr = e + g * 8 + hi * 4;
      long ro = ((long)(b * S_ + q0 + qr) * H_ + h) * DH_ + q;
      ctx[ro] = f2b(o0[g * 4 + e] * iv[e]);
      ctx[ro + 32] = f2b(o1[g * 4 + e] * iv[e]);
    }
  }
}

// ---------------- fused residual + LayerNorm ----------------
__global__ __launch_bounds__(256) void k_ln(const float* __restrict__ a, const float* __restrict__ res,
                                            const float* __restrict__ gamma, const float* __restrict__ beta,
                                            float* __restrict__ outF, u16* __restrict__ outB) {
  const int row = blockIdx.x, t = threadIdx.x;
  const long base = (long)row * E_;
  float4 av = ((const float4*)(a + base))[t];
  float4 bv = ((const float4*)(res + base))[t];
  float4 s = make_float4(av.x + bv.x, av.y + bv.y, av.z + bv.z, av.w + bv.w);
  float ps = s.x + s.y + s.z + s.w;
  float pq = s.x * s.x + s.y * s.y + s.z * s.z + s.w * s.w;
#pragma unroll
  for (int xm = 32; xm >= 1; xm >>= 1) { ps += __shfl_xor(ps, xm); pq += __shfl_xor(pq, xm); }
  __shared__ float red[8];
  int w = t >> 6, lane = t & 63;
  if (lane == 0) { red[w] = ps; red[4 + w] = pq; }
  __syncthreads();
  ps = red[0] + red[1] + red[2] + red[3];
  pq = red[4] + red[5] + red[6] + red[7];
  float mu = ps * (1.f / E_);
  float rs = rsqrtf(pq * (1.f / E_) - mu * mu + 1e-5f);
  float4 gv = ((const float4*)gamma)[t];
  float4 be = ((const float4*)beta)[t];
  float4 o = make_float4((s.x - mu) * rs * gv.x + be.x, (s.y - mu) * rs * gv.y + be.y,
                         (s.z - mu) * rs * gv.z + be.z, (s.w - mu) * rs * gv.w + be.w);
  ((float4*)(outF + base))[t] = o;
  if (outB) {
    ushort4 ob; ob.x = f2b(o.x); ob.y = f2b(o.y); ob.z = f2b(o.z); ob.w = f2b(o.w);
    ((ushort4*)(outB + base))[t] = ob;
  }
}

extern "C" void kernel_launch(void* const* d_in, const int* in_sizes, int n_in,
                              void* d_out, int out_size, void* d_ws, size_t ws_size,
                              hipStream_t stream) {
  const float* x  = (const float*)d_in[0];
  const int* mask = (const int*)d_in[1];
  const float* wq = (const float*)d_in[2];
  const float* wk = (const float*)d_in[3];
  const float* wv = (const float*)d_in[4];
  const float* wo = (const float*)d_in[5];
  const float* bo = (const float*)d_in[6];
  const float* w1 = (const float*)d_in[7];
  const float* b1 = (const float*)d_in[8];
  const float* w2 = (const float*)d_in[9];
  const float* b2 = (const float*)d_in[10];
  const float* gamma = (const float*)d_in[11];
  const float* beta  = (const float*)d_in[12];
  float* out = (float*)d_out;

  char* ws = (char*)d_ws;
  const size_t MB = 1024ull * 1024ull;
  u16* xb  = (u16*)(ws + 0);         // 16MB, reused as ctx after QKV
  u16* wqt = (u16*)(ws + 16 * MB);   // wq/wk/wv transposed, CONTIGUOUS (fused QKV gemm)
  u16* wkt = (u16*)(ws + 18 * MB);
  u16* wvt = (u16*)(ws + 20 * MB);
  u16* wot = (u16*)(ws + 22 * MB);
  u16* w1t = (u16*)(ws + 24 * MB);
  u16* w2t = (u16*)(ws + 26 * MB);
  u16* qb  = (u16*)(ws + 28 * MB);   // bh-major [B,H,S,DH]; reused as ff1 after attention
  u16* kb  = (u16*)(ws + 44 * MB);
  u16* vb  = (u16*)(ws + 60 * MB);
  float* ao = (float*)(ws + 76 * MB);  // 32MB, reused as ff2 after LN1
  float* hf = (float*)(ws + 108 * MB); // 32MB
  u16* hb  = (u16*)(ws + 140 * MB);    // 16MB
  u16* ctx = xb;
  u16* ff1 = qb;
  float* ff2 = ao;

  const int n4 = B_ * S_ * E_ / 4;
  k_cast<<<n4 / 256, 256, 0, stream>>>(x, xb, n4);
  dim3 tg(E_ / 32, E_ / 32), tb(32, 8);
  k_castT<<<tg, tb, 0, stream>>>(wq, wqt, E_, E_);
  k_castT<<<tg, tb, 0, stream>>>(wk, wkt, E_, E_);
  k_castT<<<tg, tb, 0, stream>>>(wv, wvt, E_, E_);
  k_castT<<<tg, tb, 0, stream>>>(wo, wot, E_, E_);
  k_castT<<<tg, tb, 0, stream>>>(w1, w1t, E_, E_);
  k_castT<<<tg, tb, 0, stream>>>(w2, w2t, E_, E_);

  // fused QKV: Bt = [wqt;wkt;wvt] (contiguous), N=3072, permuted bh-major write
  k_gemm<<<dim3(64, 24), 256, 0, stream>>>(xb, wqt, 3072, 1024, nullptr, 0, 1,
                                           nullptr, nullptr, qb, kb, vb);

  k_attn<<<dim3(B_ * H_, S_ / 256), 512, 0, stream>>>(qb, kb, vb, mask, ctx);

  dim3 gg(64, 8);
  k_gemm<<<gg, 256, 0, stream>>>(ctx, wot, 1024, 1024, bo, 0, 0, ao, nullptr,
                                 nullptr, nullptr, nullptr);
  k_ln<<<B_ * S_, 256, 0, stream>>>(ao, x, gamma, beta, hf, hb);
  k_gemm<<<gg, 256, 0, stream>>>(hb, w1t, 1024, 1024, b1, 1, 0, nullptr, ff1,
                                 nullptr, nullptr, nullptr);
  k_gemm<<<gg, 256, 0, stream>>>(ff1, w2t, 1024, 1024, b2, 0, 0, ff2, nullptr,
                                 nullptr, nullptr, nullptr);
  k_ln<<<B_ * S_, 256, 0, stream>>>(ff2, hf, gamma, beta, out, nullptr);
}

// Round 3
// 330.405 us; speedup vs baseline: 1.4567x; 1.0706x over previous
//
#include <hip/hip_runtime.h>
#include <hip/hip_bf16.h>

typedef short s16x8 __attribute__((ext_vector_type(8)));
typedef float f32x4 __attribute__((ext_vector_type(4)));
typedef float f32x16 __attribute__((ext_vector_type(16)));
typedef unsigned short u16;

#define B_ 4
#define S_ 2048
#define E_ 1024
#define H_ 16
#define DH_ 64

__device__ __forceinline__ u16 f2b(float f) {
  union { float f; unsigned u; } x; x.f = f;
  unsigned r = (x.u + 0x7fffu + ((x.u >> 16) & 1u)) >> 16;
  return (u16)r;
}

__device__ __forceinline__ float b2f(u16 v) {
  union { unsigned u; float f; } x; x.u = ((unsigned)v) << 16; return x.f;
}

__device__ __forceinline__ unsigned pk2(float lo, float hi) {
  __hip_bfloat162 h = __float22bfloat162_rn(float2{lo, hi});
  union { __hip_bfloat162 h; unsigned u; } c; c.h = h; return c.u;
}

// exchange x_hi <-> y_lo across the lane<32 / lane>=32 split, 1 shuffle:
// each lane only needs ONE foreign word (lane<32 needs partner's x, lane>=32 partner's y)
__device__ __forceinline__ void xsw(unsigned& x, unsigned& y, int hi) {
  unsigned s = hi ? x : y;
  unsigned r = (unsigned)__shfl_xor((int)s, 32);
  unsigned nx = hi ? r : x;
  unsigned ny = hi ? y : r;
  x = nx; y = ny;
}

__device__ __forceinline__ void async16(const void* g, void* l) {
  __builtin_amdgcn_global_load_lds((const __attribute__((address_space(1))) void*)g,
                                   (__attribute__((address_space(3))) void*)l,
                                   16, 0, 0);
}

// ---------------- cast f32 -> bf16 ----------------
__global__ __launch_bounds__(256) void k_cast(const float* __restrict__ in,
                                              u16* __restrict__ out, int n4) {
  int i = blockIdx.x * 256 + threadIdx.x;
  if (i >= n4) return;
  float4 v = ((const float4*)in)[i];
  ushort4 o;
  o.x = f2b(v.x); o.y = f2b(v.y); o.z = f2b(v.z); o.w = f2b(v.w);
  ((ushort4*)out)[i] = o;
}

// ---------------- cast + transpose weight: W[K][N] f32 -> Wt[N][K] bf16 ----------------
__global__ __launch_bounds__(256) void k_castT(const float* __restrict__ in,
                                               u16* __restrict__ out, int K, int N) {
  __shared__ float tile[32][33];
  int k0 = blockIdx.x * 32, n0 = blockIdx.y * 32;
  int tx = threadIdx.x, ty = threadIdx.y;
#pragma unroll
  for (int i = 0; i < 32; i += 8)
    tile[ty + i][tx] = in[(long)(k0 + ty + i) * N + n0 + tx];
  __syncthreads();
#pragma unroll
  for (int i = 0; i < 32; i += 8)
    out[(long)(n0 + ty + i) * K + k0 + tx] = f2b(tile[tx][ty + i]);
}

// ---------------- GEMM: C[M,N] = A[M,K](bf16) * Bt[N,K]^T(bf16) ----------------
__global__ __launch_bounds__(256, 2) void k_gemm(
    const u16* __restrict__ A, const u16* __restrict__ Bt,
    int N, int K,
    const float* __restrict__ bias, int relu, int mode,
    float* __restrict__ outF, u16* __restrict__ outB,
    u16* __restrict__ oq, u16* __restrict__ ok, u16* __restrict__ ov) {
  __shared__ __align__(16) u16 Al[128 * 32];
  __shared__ __align__(16) u16 Bl[128 * 32];
  const int t = threadIdx.x;
  const int lane = t & 63, w = t >> 6;
  const int g = lane >> 4, li = lane & 15;
  const int wr = w >> 1, wc = w & 1;
  const int bm = blockIdx.x * 128, bn = blockIdx.y * 128;

  f32x4 acc[4][4] = {};

  const long ar0 = bm + (t >> 2), ar1 = bm + ((256 + t) >> 2);
  const long br0 = bn + (t >> 2), br1 = bn + ((256 + t) >> 2);
  const int c0 = (t & 3) * 8, c1 = ((256 + t) & 3) * 8;
  u16* aD0 = &Al[(w * 64) * 8];
  u16* aD1 = &Al[(256 + w * 64) * 8];
  u16* bD0 = &Bl[(w * 64) * 8];
  u16* bD1 = &Bl[(256 + w * 64) * 8];

  for (int kt = 0; kt < K; kt += 32) {
    async16(&A[ar0 * K + kt + c0], aD0);
    async16(&A[ar1 * K + kt + c1], aD1);
    async16(&Bt[br0 * K + kt + c0], bD0);
    async16(&Bt[br1 * K + kt + c1], bD1);
    __syncthreads();
    s16x8 af[4], bf[4];
#pragma unroll
    for (int mi = 0; mi < 4; ++mi)
      af[mi] = *(const s16x8*)&Al[(wr * 64 + mi * 16 + li) * 32 + g * 8];
#pragma unroll
    for (int nf = 0; nf < 4; ++nf)
      bf[nf] = *(const s16x8*)&Bl[(wc * 64 + nf * 16 + li) * 32 + g * 8];
#pragma unroll
    for (int mi = 0; mi < 4; ++mi)
#pragma unroll
      for (int nf = 0; nf < 4; ++nf)
        acc[mi][nf] = __builtin_amdgcn_mfma_f32_16x16x32_bf16(af[mi], bf[nf], acc[mi][nf], 0, 0, 0);
    __syncthreads();
  }

#pragma unroll
  for (int mi = 0; mi < 4; ++mi)
#pragma unroll
    for (int nf = 0; nf < 4; ++nf) {
      int col = bn + wc * 64 + nf * 16 + li;
      if (mode == 1) {
        int which = col >> 10, cc = col & 1023;
        int hh = cc >> 6, dd = cc & 63;
        u16* dst = which == 0 ? oq : (which == 1 ? ok : ov);
        float scl = which == 0 ? 0.125f : 1.f;
#pragma unroll
        for (int r = 0; r < 4; ++r) {
          long row = bm + wr * 64 + mi * 16 + g * 4 + r;
          int b2 = (int)(row >> 11), ss = (int)(row & 2047);
          dst[(((long)b2 * H_ + hh) * S_ + ss) * DH_ + dd] = f2b(acc[mi][nf][r] * scl);
        }
      } else {
        float bv = bias ? bias[col] : 0.f;
#pragma unroll
        for (int r = 0; r < 4; ++r) {
          long row = bm + wr * 64 + mi * 16 + g * 4 + r;
          float v = acc[mi][nf][r] + bv;
          if (relu) v = fmaxf(v, 0.f);
          if (outF) outF[row * N + col] = v;
          if (outB) outB[row * N + col] = f2b(v);
        }
      }
    }
}

// ---------------- flash attention, pipelined swapped-QK^T 32x32 ----------------
// grid (B*H, S/256); 8 waves x 32 q-rows. 3-buffer LDS ring, 1 barrier/tile.
// iter i: WRITEKV(i+1) | barrier | QK-MFMA(i+1) | LOAD(i+2) | softmax(i) | PV(i)
// -> QK MFMAs of i+1 execute while softmax(i) runs on the VALU.
__global__ __launch_bounds__(512, 1) void k_attn(
    const u16* __restrict__ Q, const u16* __restrict__ Kg, const u16* __restrict__ Vg,
    const int* __restrict__ mask, u16* __restrict__ ctx) {
  __shared__ __align__(16) u16 Kl[3][64 * 64];   // [key][dh], XOR-swizzled rows
  __shared__ __align__(16) u16 Vt[3][64 * 72];   // [dh][key+pad8]
  __shared__ __align__(16) float MBs[S_];
  __shared__ __align__(16) float BC[8 * 32];
  const int t = threadIdx.x;
  const int lane = t & 63, wid = t >> 6;
  const int q = lane & 31, hi = lane >> 5;
  const int bh = blockIdx.x;
  const int b = bh >> 4, h = bh & 15;
  const long bhoff = (long)bh * S_ * DH_;
  const int q0 = blockIdx.y * 256 + wid * 32;
  const int skey = t >> 3, sdj = t & 7;
  const int NT = S_ / 64;

  {  // stage additive mask bias once
    int4 m4 = ((const int4*)(mask + (long)b * S_))[t];
    float4 f;
    f.x = m4.x ? 0.f : -1e10f; f.y = m4.y ? 0.f : -1e10f;
    f.z = m4.z ? 0.f : -1e10f; f.w = m4.w ? 0.f : -1e10f;
    ((float4*)MBs)[t] = f;
  }

  s16x8 qf[4];
  {
    const u16* Qp = Q + bhoff + (long)(q0 + q) * DH_;
#pragma unroll
    for (int c = 0; c < 4; ++c) qf[c] = *(const s16x8*)(Qp + c * 16 + hi * 8);
  }

  s16x8 kreg, vreg;
#define LOADKV(TI) { \
    kreg = *(const s16x8*)(Kg + bhoff + (long)((TI) * 64 + skey) * DH_ + sdj * 8); \
    vreg = *(const s16x8*)(Vg + bhoff + (long)((TI) * 64 + lane) * DH_ + wid * 8); }
#define WRITEKV(BUF) { \
    *(s16x8*)((char*)&Kl[BUF][0] + skey * 128 + ((sdj * 16) ^ ((skey & 7) << 4))) = kreg; \
    _Pragma("unroll") \
    for (int j = 0; j < 8; ++j) Vt[BUF][(wid * 8 + j) * 72 + lane] = (u16)vreg[j]; }

  const int swz = (q & 7) << 4;
#define QKSTEP(S0, S1, BUF) { \
    const char* Kc = (const char*)&Kl[BUF][0]; \
    _Pragma("unroll") \
    for (int c = 0; c < 4; ++c) { \
      s16x8 kf0 = *(const s16x8*)(Kc + q * 128 + ((c * 32 + hi * 16) ^ swz)); \
      s16x8 kf1 = *(const s16x8*)(Kc + (32 + q) * 128 + ((c * 32 + hi * 16) ^ swz)); \
      S0 = __builtin_amdgcn_mfma_f32_32x32x16_bf16(kf0, qf[c], S0, 0, 0, 0); \
      S1 = __builtin_amdgcn_mfma_f32_32x32x16_bf16(kf1, qf[c], S1, 0, 0, 0); \
    } }

#define SOFTPV(S0, S1, TI) { \
    const int kt = (TI) * 64; \
    const u16* Vc = &Vt[(TI) % 3][0]; \
    float p[32]; \
    float tmax = -1e30f; \
    _Pragma("unroll") \
    for (int g4 = 0; g4 < 4; ++g4) { \
      f32x4 mb0 = *(const f32x4*)&MBs[kt + g4 * 8 + hi * 4]; \
      f32x4 mb1 = *(const f32x4*)&MBs[kt + 32 + g4 * 8 + hi * 4]; \
      _Pragma("unroll") \
      for (int e = 0; e < 4; ++e) { \
        float v0 = S0[g4 * 4 + e] + mb0[e]; \
        float v1 = S1[g4 * 4 + e] + mb1[e]; \
        p[g4 * 4 + e] = v0; p[16 + g4 * 4 + e] = v1; \
        tmax = fmaxf(tmax, fmaxf(v0, v1)); \
      } \
    } \
    tmax = fmaxf(tmax, __shfl_xor(tmax, 32)); \
    if (!__all(tmax <= m_run + 8.f)) { \
      float mnew = fmaxf(m_run, tmax); \
      float corr = __expf(m_run - mnew); \
      m_run = mnew; l_run *= corr; \
      if (lane < 32) BC[wid * 32 + q] = corr; \
      asm volatile("s_waitcnt lgkmcnt(0)" ::: "memory"); \
      _Pragma("unroll") \
      for (int g4 = 0; g4 < 4; ++g4) { \
        f32x4 cv = *(const f32x4*)&BC[wid * 32 + g4 * 8 + hi * 4]; \
        _Pragma("unroll") \
        for (int e = 0; e < 4; ++e) { o0[g4 * 4 + e] *= cv[e]; o1[g4 * 4 + e] *= cv[e]; } \
      } \
    } \
    float ps = 0.f; \
    _Pragma("unroll") \
    for (int j = 0; j < 32; ++j) { float pv = __expf(p[j] - m_run); p[j] = pv; ps += pv; } \
    l_run += ps; \
    _Pragma("unroll") \
    for (int c = 0; c < 4; ++c) { \
      unsigned X1 = pk2(p[c * 8 + 0], p[c * 8 + 1]); \
      unsigned X2 = pk2(p[c * 8 + 2], p[c * 8 + 3]); \
      unsigned Y1 = pk2(p[c * 8 + 4], p[c * 8 + 5]); \
      unsigned Y2 = pk2(p[c * 8 + 6], p[c * 8 + 7]); \
      xsw(X1, Y1, hi); xsw(X2, Y2, hi); \
      union { unsigned u[4]; s16x8 v; } pu; \
      pu.u[0] = X1; pu.u[1] = X2; pu.u[2] = Y1; pu.u[3] = Y2; \
      s16x8 vb0 = *(const s16x8*)(Vc + (long)q * 72 + c * 16 + hi * 8); \
      s16x8 vb1 = *(const s16x8*)(Vc + (long)(32 + q) * 72 + c * 16 + hi * 8); \
      o0 = __builtin_amdgcn_mfma_f32_32x32x16_bf16(pu.v, vb0, o0, 0, 0, 0); \
      o1 = __builtin_amdgcn_mfma_f32_32x32x16_bf16(pu.v, vb1, o1, 0, 0, 0); \
    } }

  // iter i: WRITEKV(i+1) | barrier | QK(i+1)->SN | LOAD(i+2) | softmax+PV(i) on SC
#define ITER(I, SC0, SC1, SN0, SN1) { \
    const int ip1 = (I) + 1; \
    if (ip1 < NT) WRITEKV(ip1 % 3); \
    __syncthreads(); \
    if (ip1 < NT) { \
      SN0 = zz; SN1 = zz; \
      QKSTEP(SN0, SN1, ip1 % 3); \
      if (ip1 + 1 < NT) LOADKV(ip1 + 1); \
    } \
    SOFTPV(SC0, SC1, I); }

  f32x16 zz = {};
  f32x16 o0 = zz, o1 = zz;
  float m_run = -1e30f, l_run = 0.f;

  // prologue: stage tile 0, issue QK(0), start loads for tile 1
  LOADKV(0);
  WRITEKV(0);
  __syncthreads();
  f32x16 sA0 = zz, sA1 = zz, sB0 = zz, sB1 = zz;
  QKSTEP(sA0, sA1, 0);
  LOADKV(1);

  for (int i = 0; i < NT; i += 2) {
    ITER(i, sA0, sA1, sB0, sB1);
    ITER(i + 1, sB0, sB1, sA0, sA1);
  }

  // epilogue
  l_run += __shfl_xor(l_run, 32);
  float inv = 1.f / fmaxf(l_run, 1e-30f);
  if (lane < 32) BC[wid * 32 + q] = inv;
  asm volatile("s_waitcnt lgkmcnt(0)" ::: "memory");
#pragma unroll
  for (int g4 = 0; g4 < 4; ++g4) {
    f32x4 iv = *(const f32x4*)&BC[wid * 32 + g4 * 8 + hi * 4];
#pragma unroll
    for (int e = 0; e < 4; ++e) {
      int qr = e + g4 * 8 + hi * 4;
      long ro = ((long)(b * S_ + q0 + qr) * H_ + h) * DH_ + q;
      ctx[ro] = f2b(o0[g4 * 4 + e] * iv[e]);
      ctx[ro + 32] = f2b(o1[g4 * 4 + e] * iv[e]);
    }
  }
#undef LOADKV
#undef WRITEKV
#undef QKSTEP
#undef SOFTPV
#undef ITER
}

// ---------------- fused residual + LayerNorm (bf16 in, f32/bf16 out) ----------------
__global__ __launch_bounds__(256) void k_lnb(const u16* __restrict__ a, const u16* __restrict__ res,
                                             const float* __restrict__ gamma, const float* __restrict__ beta,
                                             float* __restrict__ outF, u16* __restrict__ outB) {
  const int row = blockIdx.x, t = threadIdx.x;
  const long base = (long)row * E_;
  ushort4 av = ((const ushort4*)(a + base))[t];
  ushort4 rv = ((const ushort4*)(res + base))[t];
  float4 s = make_float4(b2f(av.x) + b2f(rv.x), b2f(av.y) + b2f(rv.y),
                         b2f(av.z) + b2f(rv.z), b2f(av.w) + b2f(rv.w));
  float ps = s.x + s.y + s.z + s.w;
  float pq = s.x * s.x + s.y * s.y + s.z * s.z + s.w * s.w;
#pragma unroll
  for (int xm = 32; xm >= 1; xm >>= 1) { ps += __shfl_xor(ps, xm); pq += __shfl_xor(pq, xm); }
  __shared__ float red[8];
  int w = t >> 6, lane = t & 63;
  if (lane == 0) { red[w] = ps; red[4 + w] = pq; }
  __syncthreads();
  ps = red[0] + red[1] + red[2] + red[3];
  pq = red[4] + red[5] + red[6] + red[7];
  float mu = ps * (1.f / E_);
  float rs = rsqrtf(pq * (1.f / E_) - mu * mu + 1e-5f);
  float4 gv = ((const float4*)gamma)[t];
  float4 be = ((const float4*)beta)[t];
  float4 o = make_float4((s.x - mu) * rs * gv.x + be.x, (s.y - mu) * rs * gv.y + be.y,
                         (s.z - mu) * rs * gv.z + be.z, (s.w - mu) * rs * gv.w + be.w);
  if (outF) ((float4*)(outF + base))[t] = o;
  if (outB) {
    ushort4 ob; ob.x = f2b(o.x); ob.y = f2b(o.y); ob.z = f2b(o.z); ob.w = f2b(o.w);
    ((ushort4*)(outB + base))[t] = ob;
  }
}

extern "C" void kernel_launch(void* const* d_in, const int* in_sizes, int n_in,
                              void* d_out, int out_size, void* d_ws, size_t ws_size,
                              hipStream_t stream) {
  const float* x  = (const float*)d_in[0];
  const int* mask = (const int*)d_in[1];
  const float* wq = (const float*)d_in[2];
  const float* wk = (const float*)d_in[3];
  const float* wv = (const float*)d_in[4];
  const float* wo = (const float*)d_in[5];
  const float* bo = (const float*)d_in[6];
  const float* w1 = (const float*)d_in[7];
  const float* b1 = (const float*)d_in[8];
  const float* w2 = (const float*)d_in[9];
  const float* b2 = (const float*)d_in[10];
  const float* gamma = (const float*)d_in[11];
  const float* beta  = (const float*)d_in[12];
  float* out = (float*)d_out;

  char* ws = (char*)d_ws;
  const size_t MB = 1024ull * 1024ull;
  u16* xb  = (u16*)(ws + 0);           // bf16 x, kept live through LN1
  u16* wqt = (u16*)(ws + 16 * MB);     // wq/wk/wv transposed, contiguous
  u16* wkt = (u16*)(ws + 18 * MB);
  u16* wvt = (u16*)(ws + 20 * MB);
  u16* wot = (u16*)(ws + 22 * MB);
  u16* w1t = (u16*)(ws + 24 * MB);
  u16* w2t = (u16*)(ws + 26 * MB);
  u16* qb  = (u16*)(ws + 28 * MB);     // [B,H,S,DH]; reused as ff1 after attention
  u16* kb  = (u16*)(ws + 44 * MB);     // reused as ff2b after attention
  u16* vb  = (u16*)(ws + 60 * MB);
  u16* ctx = (u16*)(ws + 76 * MB);
  u16* aob = (u16*)(ws + 92 * MB);
  u16* hb  = (u16*)(ws + 108 * MB);
  u16* ff1 = qb;
  u16* ff2b = kb;

  const int n4 = B_ * S_ * E_ / 4;
  k_cast<<<n4 / 256, 256, 0, stream>>>(x, xb, n4);
  dim3 tg(E_ / 32, E_ / 32), tb(32, 8);
  k_castT<<<tg, tb, 0, stream>>>(wq, wqt, E_, E_);
  k_castT<<<tg, tb, 0, stream>>>(wk, wkt, E_, E_);
  k_castT<<<tg, tb, 0, stream>>>(wv, wvt, E_, E_);
  k_castT<<<tg, tb, 0, stream>>>(wo, wot, E_, E_);
  k_castT<<<tg, tb, 0, stream>>>(w1, w1t, E_, E_);
  k_castT<<<tg, tb, 0, stream>>>(w2, w2t, E_, E_);

  // fused QKV: Bt = [wqt;wkt;wvt] contiguous, N=3072, permuted bh-major write
  k_gemm<<<dim3(64, 24), 256, 0, stream>>>(xb, wqt, 3072, 1024, nullptr, 0, 1,
                                           nullptr, nullptr, qb, kb, vb);

  k_attn<<<dim3(B_ * H_, S_ / 256), 512, 0, stream>>>(qb, kb, vb, mask, ctx);

  dim3 gg(64, 8);
  k_gemm<<<gg, 256, 0, stream>>>(ctx, wot, 1024, 1024, bo, 0, 0, nullptr, aob,
                                 nullptr, nullptr, nullptr);
  k_lnb<<<B_ * S_, 256, 0, stream>>>(aob, xb, gamma, beta, nullptr, hb);
  k_gemm<<<gg, 256, 0, stream>>>(hb, w1t, 1024, 1024, b1, 1, 0, nullptr, ff1,
                                 nullptr, nullptr, nullptr);
  k_gemm<<<gg, 256, 0, stream>>>(ff1, w2t, 1024, 1024, b2, 0, 0, nullptr, ff2b,
                                 nullptr, nullptr, nullptr);
  k_lnb<<<B_ * S_, 256, 0, stream>>>(ff2b, hb, gamma, beta, out, nullptr);
}